// Round 6
// baseline (110.355 us; speedup 1.0000x reference)
//
#include <hip/hip_runtime.h>
#include <hip/hip_bf16.h>

// Shapes
#define B_SZ   256
#define C_SZ   1024
#define HW     49
#define KDIM   50176        // C*H*W
#define DHID   768
#define NCLS   5

typedef __bf16 bf16x8 __attribute__((ext_vector_type(8)));
typedef float  f32x4  __attribute__((ext_vector_type(4)));

#define GLOAD_LDS16(gsrc, ldst) \
  __builtin_amdgcn_global_load_lds((__attribute__((address_space(1))) void*)(gsrc), \
                                   (__attribute__((address_space(3))) void*)(ldst), 16, 0, 0)

// ---------------------------------------------------------------------------
// Kernel A: per-(b,c) spatial max, pcam = feat*max -> bf16 (ws), copy feat -> out
// ---------------------------------------------------------------------------
__global__ __launch_bounds__(256) void pcam_kernel(const float* __restrict__ feat,
                                                   float* __restrict__ feat_out,
                                                   __bf16* __restrict__ pcam) {
  __shared__ float sv[1568];
  __shared__ float smax[32];
  const int tid = threadIdx.x;
  const size_t base = (size_t)blockIdx.x * 1568;

  const float4* src4 = (const float4*)(feat + base);
  float4* dst4 = (float4*)(feat_out + base);
  #pragma unroll
  for (int i = 0; i < 2; ++i) {
    int idx = tid + i * 256;
    if (idx < 392) {
      float4 v = src4[idx];
      dst4[idx] = v;
      ((float4*)sv)[idx] = v;
    }
  }
  __syncthreads();

  {
    const int r = tid >> 3, p = tid & 7;
    float mx = -INFINITY;
    for (int i = p; i < HW; i += 8) mx = fmaxf(mx, sv[r * HW + i]);
    #pragma unroll
    for (int off = 1; off < 8; off <<= 1) mx = fmaxf(mx, __shfl_xor(mx, off));
    if (p == 0) smax[r] = mx;
  }
  __syncthreads();

  for (int i = tid; i < 1568; i += 256) {
    int r = (i * 1338) >> 16;        // i/49 exact for i<1568
    float v = sv[i] * smax[r];
    pcam[base + i] = (__bf16)v;
  }
}

// ---------------------------------------------------------------------------
// Kernel B: split-K bf16 MFMA GEMM. ALL staging via global_load_lds DMA
// (no destination registers -> register allocator CANNOT sink the prefetch,
// which it provably did in R1-R5: VGPR_Count 52-68 can't hold acc+prefetch).
// B staged as RAW FP32 in LDS (DMA can't convert); fp32->bf16 at fragment
// read (VALU is idle). Triple-buffered, depth-2 pipeline, tapered counted
// vmcnt(6/3/0) + raw barriers — loads for steps s+1, s+2 stay in flight
// while computing step s. Per wave per step exactly 3 DMA instrs.
// BM=128 BN=128 BK=32, 8 waves (2Mx4N), LDS 72KB -> 2 blocks/CU.
// XOR swizzle on DMA SOURCE lanes (linear LDS dest, m173): A unit^=(m&3),
// B unit^=(n&7) -> swizzled fragment reads, ~2-way conflicts max.
// ---------------------------------------------------------------------------
#define BM 128
#define BN 128
#define BK 32
#define NBUF 3
#define MT 2
#define NT 6
#define KSPLIT 42
#define KSTEPS 1568         // KDIM/BK

__global__ __launch_bounds__(512, 4) void gemm1_kernel(const __bf16* __restrict__ pcam,
                                                       const float* __restrict__ W1,
                                                       float* __restrict__ h_part) {
  __shared__ __bf16 Asm[NBUF][BM * BK];   // 3 x 8KB  (bf16)
  __shared__ float  Bsm[NBUF][BN * BK];   // 3 x 16KB (fp32)

  const int tid  = threadIdx.x;
  const int lane = tid & 63;
  const int w    = tid >> 6;        // 0..7
  const int wm   = w >> 2;          // 0..1
  const int wn   = w & 3;           // 0..3
  const int bx   = blockIdx.x;      // 0..11
  const int m0   = (bx & 1) * BM;
  const int n0   = (bx >> 1) * BN;
  const int ks   = blockIdx.y;
  const int s0   = (ks * KSTEPS) / KSPLIT;
  const int s1   = ((ks + 1) * KSTEPS) / KSPLIT;

  // A DMA geometry: wave w covers rows w*16..w*16+15; lane -> row w*16+(l>>2),
  // 16B unit (l&3), source unit pre-swizzled by ^(m&3).
  const int m_d = w * 16 + (lane >> 2);
  const int ua  = (lane & 3) ^ (m_d & 3);
  const __bf16* asrc = pcam + (size_t)(m0 + m_d) * KDIM + ua * 8;

  // B DMA geometry: 2 instrs; instr covers 8 rows x 128B. lane -> row
  // rbase+(l>>3), unit (l&7) ^ (row&7). rbase multiple of 8 -> row&7=(l>>3)&7.
  const int r1  = w * 8 + (lane >> 3);
  const int ub  = (lane & 7) ^ (r1 & 7);
  const float* bsrc1 = W1 + (size_t)(n0 + r1) * KDIM + ub * 4;
  const float* bsrc2 = W1 + (size_t)(n0 + 64 + r1) * KDIM + ub * 4;

  char* aw = (char*)&Asm[0][0] + w * 1024;   // wave-uniform LDS dests
  char* bw = (char*)&Bsm[0][0] + w * 1024;

  f32x4 acc[4][2];
  #pragma unroll
  for (int i = 0; i < 4; ++i)
    #pragma unroll
    for (int j = 0; j < 2; ++j) acc[i][j] = f32x4{0.f, 0.f, 0.f, 0.f};

#define ISSUE(bi, s) do { \
    const size_t ko_ = (size_t)(s) * BK; \
    GLOAD_LDS16(asrc + ko_,  aw + (size_t)(bi) * (BM * BK * 2)); \
    GLOAD_LDS16(bsrc1 + ko_, bw + (size_t)(bi) * (BN * BK * 4)); \
    GLOAD_LDS16(bsrc2 + ko_, bw + (size_t)(bi) * (BN * BK * 4) + 8192); \
  } while (0)

#define COMPUTE(bi) do { \
    const int j_  = lane >> 4; \
    const int c_  = lane & 15; \
    bf16x8 af[4]; \
    _Pragma("unroll") \
    for (int i = 0; i < 4; ++i) { \
      const int m = wm * 64 + i * 16 + c_; \
      af[i] = *(const bf16x8*)((const char*)Asm[bi] + m * 64 + ((j_ ^ (m & 3)) << 4)); \
    } \
    bf16x8 bfr[2]; \
    _Pragma("unroll") \
    for (int jf = 0; jf < 2; ++jf) { \
      const int n = wn * 32 + jf * 16 + c_; \
      const f32x4 b0 = *(const f32x4*)((const char*)Bsm[bi] + n * 128 + (((2 * j_)     ^ (n & 7)) << 4)); \
      const f32x4 b1 = *(const f32x4*)((const char*)Bsm[bi] + n * 128 + (((2 * j_ + 1) ^ (n & 7)) << 4)); \
      bfr[jf][0] = (__bf16)b0[0]; bfr[jf][1] = (__bf16)b0[1]; \
      bfr[jf][2] = (__bf16)b0[2]; bfr[jf][3] = (__bf16)b0[3]; \
      bfr[jf][4] = (__bf16)b1[0]; bfr[jf][5] = (__bf16)b1[1]; \
      bfr[jf][6] = (__bf16)b1[2]; bfr[jf][7] = (__bf16)b1[3]; \
    } \
    _Pragma("unroll") \
    for (int i = 0; i < 4; ++i) \
      _Pragma("unroll") \
      for (int jf = 0; jf < 2; ++jf) \
        acc[i][jf] = __builtin_amdgcn_mfma_f32_16x16x32_bf16(af[i], bfr[jf], acc[i][jf], 0, 0, 0); \
  } while (0)

  // ---- prologue: fill pipeline 2 deep
  int b0i = 0, b1i = 1, b2i = 2;
  ISSUE(0, s0);
  if (s0 + 1 < s1) ISSUE(1, s0 + 1);

  for (int s = s0; s < s1; ++s) {
    if (s + 2 < s1) {
      ISSUE(b2i, s + 2);                                   // depth-2 refill
      asm volatile("s_waitcnt vmcnt(6)" ::: "memory");     // wait step s only
    } else if (s + 1 < s1) {
      asm volatile("s_waitcnt vmcnt(3)" ::: "memory");
    } else {
      asm volatile("s_waitcnt vmcnt(0)" ::: "memory");
    }
    __builtin_amdgcn_s_barrier();        // all waves' DMAs for buf s done
    COMPUTE(b0i);
    asm volatile("s_waitcnt lgkmcnt(0)" ::: "memory");
    __builtin_amdgcn_s_barrier();        // reads done before buf s is re-DMA'd
    const int t = b0i; b0i = b1i; b1i = b2i; b2i = t;
  }

  // ---- epilogue: private partial slice, coalesced float4 stores, no atomics
  float* out = h_part + (size_t)ks * DHID * B_SZ;
  #pragma unroll
  for (int i = 0; i < 4; ++i) {
    const int mb = m0 + wm * 64 + i * 16 + (lane >> 4) * 4;
    #pragma unroll
    for (int j = 0; j < 2; ++j) {
      const int n = n0 + wn * 32 + j * 16 + (lane & 15);
      *(f32x4*)(out + (size_t)n * B_SZ + mb) = acc[i][j];
    }
  }
#undef ISSUE
#undef COMPUTE
}

// ---------------------------------------------------------------------------
// Kernel C: reduce split-K partials, add b1, relu -> h[m][n]
// ---------------------------------------------------------------------------
__global__ __launch_bounds__(256) void reduce_kernel(const float* __restrict__ h_part,
                                                     const float* __restrict__ b1,
                                                     float* __restrict__ h) {
  const int n = blockIdx.x;
  const int m = threadIdx.x;
  float s = 0.f;
  #pragma unroll 6
  for (int ks = 0; ks < KSPLIT; ++ks)
    s += h_part[((size_t)ks * DHID + n) * B_SZ + m];
  float v = s + b1[n];
  h[(size_t)m * DHID + n] = v > 0.f ? v : 0.f;
}

// ---------------------------------------------------------------------------
// Kernel D: logits = h @ W2^T + b2. One wave per batch row.
// ---------------------------------------------------------------------------
__global__ __launch_bounds__(64) void head_kernel(const float* __restrict__ h,
                                                  const float* __restrict__ W2,
                                                  const float* __restrict__ b2,
                                                  float* __restrict__ logits) {
  const int m = blockIdx.x;
  const int lane = threadIdx.x;
  float hv[12];
  #pragma unroll
  for (int j = 0; j < 12; ++j) hv[j] = h[(size_t)m * DHID + j * 64 + lane];
  #pragma unroll
  for (int c = 0; c < NCLS; ++c) {
    float s = 0.f;
    #pragma unroll
    for (int j = 0; j < 12; ++j) s += hv[j] * W2[c * DHID + j * 64 + lane];
    #pragma unroll
    for (int off = 32; off > 0; off >>= 1) s += __shfl_xor(s, off);
    if (lane == 0) logits[m * NCLS + c] = s + b2[c];
  }
}

// ---------------------------------------------------------------------------
extern "C" void kernel_launch(void* const* d_in, const int* in_sizes, int n_in,
                              void* d_out, int out_size, void* d_ws, size_t ws_size,
                              hipStream_t stream) {
  const float* feat = (const float*)d_in[0];
  const float* W1   = (const float*)d_in[1];
  const float* b1   = (const float*)d_in[2];
  const float* W2   = (const float*)d_in[3];
  const float* b2   = (const float*)d_in[4];

  float* logits   = (float*)d_out;
  float* feat_out = (float*)d_out + (size_t)B_SZ * NCLS;

  char* ws = (char*)d_ws;
  __bf16* pcam   = (__bf16*)ws;                                   // 25.7 MB
  float*  h_part = (float*)(ws + (size_t)B_SZ * KDIM * 2);        // 33 MB
  float*  h      = (float*)(ws + (size_t)B_SZ * KDIM * 2
                               + (size_t)KSPLIT * DHID * B_SZ * 4); // 786 KB

  pcam_kernel<<<(B_SZ * C_SZ) / 32, 256, 0, stream>>>(feat, feat_out, pcam);
  gemm1_kernel<<<dim3(MT * NT, KSPLIT), 512, 0, stream>>>(pcam, W1, h_part);
  reduce_kernel<<<DHID, 256, 0, stream>>>(h_part, b1, h);
  head_kernel<<<B_SZ, 64, 0, stream>>>(h, W2, b2, logits);
}

// Round 7
// 106.813 us; speedup vs baseline: 1.0332x; 1.0332x over previous
//
#include <hip/hip_runtime.h>
#include <hip/hip_bf16.h>

// Shapes
#define B_SZ   256
#define C_SZ   1024
#define HW     49
#define KDIM   50176        // C*H*W
#define DHID   768
#define NCLS   5

typedef __bf16 bf16x8 __attribute__((ext_vector_type(8)));
typedef float  f32x4  __attribute__((ext_vector_type(4)));

#define GLOAD_LDS16(gsrc, ldst) \
  __builtin_amdgcn_global_load_lds((__attribute__((address_space(1))) void*)(gsrc), \
                                   (__attribute__((address_space(3))) void*)(ldst), 16, 0, 0)

// ---------------------------------------------------------------------------
// Kernel A: per-(b,c) spatial max, pcam = feat*max -> bf16 (ws), copy feat -> out
// ---------------------------------------------------------------------------
__global__ __launch_bounds__(256) void pcam_kernel(const float* __restrict__ feat,
                                                   float* __restrict__ feat_out,
                                                   __bf16* __restrict__ pcam) {
  __shared__ float sv[1568];
  __shared__ float smax[32];
  const int tid = threadIdx.x;
  const size_t base = (size_t)blockIdx.x * 1568;

  const float4* src4 = (const float4*)(feat + base);
  float4* dst4 = (float4*)(feat_out + base);
  #pragma unroll
  for (int i = 0; i < 2; ++i) {
    int idx = tid + i * 256;
    if (idx < 392) {
      float4 v = src4[idx];
      dst4[idx] = v;
      ((float4*)sv)[idx] = v;
    }
  }
  __syncthreads();

  {
    const int r = tid >> 3, p = tid & 7;
    float mx = -INFINITY;
    for (int i = p; i < HW; i += 8) mx = fmaxf(mx, sv[r * HW + i]);
    #pragma unroll
    for (int off = 1; off < 8; off <<= 1) mx = fmaxf(mx, __shfl_xor(mx, off));
    if (p == 0) smax[r] = mx;
  }
  __syncthreads();

  for (int i = tid; i < 1568; i += 256) {
    int r = (i * 1338) >> 16;        // i/49 exact for i<1568
    float v = sv[i] * smax[r];
    pcam[base + i] = (__bf16)v;
  }
}

// ---------------------------------------------------------------------------
// Kernel B (v5): Theory-Z geometry. R1-R6 all read W1 as thousands of
// 128-256B-granule strided streams -> ~2.4 TB/s HBM (vs 7 TB/s sequential on
// this chip). This version: BM=256 (FULL M: W1 streamed exactly once, no
// duplication), BN=64, BK=64 -> 256B/row/step with depth-2 in flight (512B
// windows), 252 blocks total (10x fewer streams). All staging via
// global_load_lds DMA (unsinkable), NBUF=3, tapered vmcnt(12/6/0).
// LDS 144KB -> 1 block/CU. A (pcam) is L3-resident; re-read 12x = 308MB L3.
// XOR swizzle on DMA SOURCE (linear LDS dest): A 16B-unit ^= (m&7),
// B 32B-granule ^= (r&7) -> fragment ds_reads are 2-way max.
// ---------------------------------------------------------------------------
#define BM 256
#define BN 64
#define BK 64
#define NBUF 3
#define NT 12
#define KSPLIT 21
#define KSTEPS 784          // KDIM/BK
#define ASZ (BM * BK * 2)   // 32768 B per A buffer
#define BSZ (BN * BK * 4)   // 16384 B per B buffer

__global__ __launch_bounds__(512, 2) void gemm1_kernel(const __bf16* __restrict__ pcam,
                                                       const float* __restrict__ W1,
                                                       float* __restrict__ h_part) {
  __shared__ __bf16 Asm[NBUF][BM * BK];   // 3 x 32 KB
  __shared__ float  Bsm[NBUF][BN * BK];   // 3 x 16 KB

  const int tid  = threadIdx.x;
  const int lane = tid & 63;
  const int w    = tid >> 6;        // 0..7
  const int wm   = w >> 2;          // 0..1 : m-slab of 128
  const int wn   = w & 3;           // 0..3 : n-slab of 16
  const int n0   = blockIdx.x * BN;
  const int ks   = blockIdx.y;
  const int s0   = (ks * KSTEPS) / KSPLIT;
  const int s1   = ((ks + 1) * KSTEPS) / KSPLIT;

  // A DMA: 4 instrs/wave; instr (w*4+it): 16B-unit ug=(w*4+it)*64+lane,
  // row m=ug>>3 (8 units/row), source unit = (ug&7)^(m&7).
  unsigned a_off0, a_off1, a_off2, a_off3;
  {
    unsigned ug, m;
    ug = (w * 4 + 0) * 64 + lane; m = ug >> 3; a_off0 = m * (unsigned)KDIM + (((ug & 7) ^ (m & 7)) * 8u);
    ug = (w * 4 + 1) * 64 + lane; m = ug >> 3; a_off1 = m * (unsigned)KDIM + (((ug & 7) ^ (m & 7)) * 8u);
    ug = (w * 4 + 2) * 64 + lane; m = ug >> 3; a_off2 = m * (unsigned)KDIM + (((ug & 7) ^ (m & 7)) * 8u);
    ug = (w * 4 + 3) * 64 + lane; m = ug >> 3; a_off3 = m * (unsigned)KDIM + (((ug & 7) ^ (m & 7)) * 8u);
  }
  // B DMA: 2 instrs/wave; 16B-unit ug=(w*2+it)*64+lane, row r=ug>>4 (16/row),
  // 32B-granule g_phys=(ug&15)>>1, half=(ug&1); source granule = g_phys^(r&7).
  unsigned b_off0, b_off1;
  {
    unsigned ug, r, up;
    ug = (w * 2 + 0) * 64 + lane; r = ug >> 4; up = ug & 15;
    b_off0 = (unsigned)(n0 + r) * (unsigned)KDIM + (((up >> 1) ^ (r & 7)) * 8u) + ((up & 1) * 4u);
    ug = (w * 2 + 1) * 64 + lane; r = ug >> 4; up = ug & 15;
    b_off1 = (unsigned)(n0 + r) * (unsigned)KDIM + (((up >> 1) ^ (r & 7)) * 8u) + ((up & 1) * 4u);
  }

  f32x4 acc[8];
  #pragma unroll
  for (int i = 0; i < 8; ++i) acc[i] = f32x4{0.f, 0.f, 0.f, 0.f};

#define ISSUE(bi, s) do { \
    const unsigned ka = (unsigned)(s) * BK; \
    GLOAD_LDS16(pcam + a_off0 + ka, (char*)Asm + (size_t)(bi) * ASZ + (w * 4 + 0) * 1024); \
    GLOAD_LDS16(pcam + a_off1 + ka, (char*)Asm + (size_t)(bi) * ASZ + (w * 4 + 1) * 1024); \
    GLOAD_LDS16(pcam + a_off2 + ka, (char*)Asm + (size_t)(bi) * ASZ + (w * 4 + 2) * 1024); \
    GLOAD_LDS16(pcam + a_off3 + ka, (char*)Asm + (size_t)(bi) * ASZ + (w * 4 + 3) * 1024); \
    GLOAD_LDS16(W1 + b_off0 + ka,   (char*)Bsm + (size_t)(bi) * BSZ + (w * 2 + 0) * 1024); \
    GLOAD_LDS16(W1 + b_off1 + ka,   (char*)Bsm + (size_t)(bi) * BSZ + (w * 2 + 1) * 1024); \
  } while (0)

#define COMPUTE(bi) do { \
    const int j_ = lane >> 4; \
    const int c_ = lane & 15; \
    _Pragma("unroll") \
    for (int ksub = 0; ksub < 2; ++ksub) { \
      bf16x8 af[8]; \
      _Pragma("unroll") \
      for (int i = 0; i < 8; ++i) { \
        const int m = wm * 128 + i * 16 + c_; \
        const int u = ksub * 4 + j_; \
        af[i] = *(const bf16x8*)((const char*)Asm + (size_t)(bi) * ASZ + m * 128 + ((u ^ (m & 7)) << 4)); \
      } \
      const int r  = wn * 16 + c_; \
      const int g  = ksub * 4 + j_; \
      const int gp = g ^ (r & 7); \
      const f32x4 v0 = *(const f32x4*)((const char*)Bsm + (size_t)(bi) * BSZ + r * 256 + gp * 32); \
      const f32x4 v1 = *(const f32x4*)((const char*)Bsm + (size_t)(bi) * BSZ + r * 256 + gp * 32 + 16); \
      bf16x8 bf; \
      bf[0] = (__bf16)v0[0]; bf[1] = (__bf16)v0[1]; bf[2] = (__bf16)v0[2]; bf[3] = (__bf16)v0[3]; \
      bf[4] = (__bf16)v1[0]; bf[5] = (__bf16)v1[1]; bf[6] = (__bf16)v1[2]; bf[7] = (__bf16)v1[3]; \
      _Pragma("unroll") \
      for (int i = 0; i < 8; ++i) \
        acc[i] = __builtin_amdgcn_mfma_f32_16x16x32_bf16(af[i], bf, acc[i], 0, 0, 0); \
    } \
  } while (0)

  // ---- prologue: fill pipeline 2 deep
  int b0i = 0, b1i = 1, b2i = 2;
  ISSUE(0, s0);
  if (s0 + 1 < s1) ISSUE(1, s0 + 1);

  for (int s = s0; s < s1; ++s) {
    if (s + 2 < s1) {
      ISSUE(b2i, s + 2);                                   // depth-2 refill
      asm volatile("s_waitcnt vmcnt(12)" ::: "memory");    // wait step s only
    } else if (s + 1 < s1) {
      asm volatile("s_waitcnt vmcnt(6)" ::: "memory");
    } else {
      asm volatile("s_waitcnt vmcnt(0)" ::: "memory");
    }
    __builtin_amdgcn_s_barrier();        // all waves' DMAs for buf s done
    COMPUTE(b0i);
    asm volatile("s_waitcnt lgkmcnt(0)" ::: "memory");
    __builtin_amdgcn_s_barrier();        // reads done before buf is re-DMA'd
    const int t = b0i; b0i = b1i; b1i = b2i; b2i = t;
  }

  // ---- epilogue: private partial slice, coalesced float4 stores, no atomics
  float* out = h_part + (size_t)ks * DHID * B_SZ;
  #pragma unroll
  for (int i = 0; i < 8; ++i) {
    const int mb = wm * 128 + i * 16 + (lane >> 4) * 4;
    const int n  = n0 + wn * 16 + (lane & 15);
    *(f32x4*)(out + (size_t)n * B_SZ + mb) = acc[i];
  }
#undef ISSUE
#undef COMPUTE
}

// ---------------------------------------------------------------------------
// Kernel C: reduce split-K partials, add b1, relu -> h[m][n]
// ---------------------------------------------------------------------------
__global__ __launch_bounds__(256) void reduce_kernel(const float* __restrict__ h_part,
                                                     const float* __restrict__ b1,
                                                     float* __restrict__ h) {
  const int n = blockIdx.x;
  const int m = threadIdx.x;
  float s = 0.f;
  #pragma unroll
  for (int ks = 0; ks < KSPLIT; ++ks)
    s += h_part[((size_t)ks * DHID + n) * B_SZ + m];
  float v = s + b1[n];
  h[(size_t)m * DHID + n] = v > 0.f ? v : 0.f;
}

// ---------------------------------------------------------------------------
// Kernel D: logits = h @ W2^T + b2. One wave per batch row.
// ---------------------------------------------------------------------------
__global__ __launch_bounds__(64) void head_kernel(const float* __restrict__ h,
                                                  const float* __restrict__ W2,
                                                  const float* __restrict__ b2,
                                                  float* __restrict__ logits) {
  const int m = blockIdx.x;
  const int lane = threadIdx.x;
  float hv[12];
  #pragma unroll
  for (int j = 0; j < 12; ++j) hv[j] = h[(size_t)m * DHID + j * 64 + lane];
  #pragma unroll
  for (int c = 0; c < NCLS; ++c) {
    float s = 0.f;
    #pragma unroll
    for (int j = 0; j < 12; ++j) s += hv[j] * W2[c * DHID + j * 64 + lane];
    #pragma unroll
    for (int off = 32; off > 0; off >>= 1) s += __shfl_xor(s, off);
    if (lane == 0) logits[m * NCLS + c] = s + b2[c];
  }
}

// ---------------------------------------------------------------------------
extern "C" void kernel_launch(void* const* d_in, const int* in_sizes, int n_in,
                              void* d_out, int out_size, void* d_ws, size_t ws_size,
                              hipStream_t stream) {
  const float* feat = (const float*)d_in[0];
  const float* W1   = (const float*)d_in[1];
  const float* b1   = (const float*)d_in[2];
  const float* W2   = (const float*)d_in[3];
  const float* b2   = (const float*)d_in[4];

  float* logits   = (float*)d_out;
  float* feat_out = (float*)d_out + (size_t)B_SZ * NCLS;

  char* ws = (char*)d_ws;
  __bf16* pcam   = (__bf16*)ws;                                   // 25.7 MB
  float*  h_part = (float*)(ws + (size_t)B_SZ * KDIM * 2);        // 21*768*256*4 = 16.5 MB
  float*  h      = (float*)(ws + (size_t)B_SZ * KDIM * 2
                               + (size_t)KSPLIT * DHID * B_SZ * 4); // 786 KB

  pcam_kernel<<<(B_SZ * C_SZ) / 32, 256, 0, stream>>>(feat, feat_out, pcam);
  gemm1_kernel<<<dim3(NT, KSPLIT), 512, 0, stream>>>(pcam, W1, h_part);
  reduce_kernel<<<DHID, 256, 0, stream>>>(h_part, b1, h);
  head_kernel<<<B_SZ, 64, 0, stream>>>(h, W2, b2, logits);
}